// Round 4
// baseline (2292.008 us; speedup 1.0000x reference)
//
#include <hip/hip_runtime.h>

#define DIM 64
#define BSHIFT 8                 // 256 node ids per bucket
#define BWIDTH (1 << BSHIFT)

__device__ inline float wave_reduce_sum(float v) {
#pragma unroll
    for (int m = 32; m >= 1; m >>= 1) v += __shfl_xor(v, m, 64);
    return v;
}

// ---------- pass A1: bucket histogram ----------
__global__ void bucket_count(const int* __restrict__ rows, const int* __restrict__ cols,
                             int* __restrict__ bcnt, int nu, int E) {
    int e = blockIdx.x * blockDim.x + threadIdx.x;
    if (e >= E) return;
    atomicAdd(&bcnt[rows[e] >> BSHIFT], 1);
    atomicAdd(&bcnt[(nu + cols[e]) >> BSHIFT], 1);
}

// ---------- single-block exclusive scan (n <= 4095) ----------
// bbase[i] = exclusive prefix, bbase[n] = total; bcur = copy of bbase
__global__ void exscan_small(const int* __restrict__ bcnt, int* __restrict__ bbase,
                             int* __restrict__ bcur, int n) {
    __shared__ int lds[1024];
    int t = threadIdx.x;
    int base = t * 4;
    int c[4]; int s = 0;
#pragma unroll
    for (int k = 0; k < 4; k++) { int i = base + k; c[k] = (i < n) ? bcnt[i] : 0; s += c[k]; }
    lds[t] = s; __syncthreads();
    for (int off = 1; off < 1024; off <<= 1) {
        int add = (t >= off) ? lds[t - off] : 0;
        __syncthreads();
        lds[t] += add;
        __syncthreads();
    }
    int run = lds[t] - s;
#pragma unroll
    for (int k = 0; k < 4; k++) {
        int i = base + k;
        if (i < n)       { bbase[i] = run; bcur[i] = run; }
        else if (i == n) { bbase[i] = run; }
        run += c[k];
    }
}

// ---------- pass A2: scatter (dst,src) records into bucket regions ----------
__global__ void scatter_recs(const int* __restrict__ rows, const int* __restrict__ cols,
                             int* __restrict__ bcur, uint2* __restrict__ recs,
                             int nu, int E) {
    int e = blockIdx.x * blockDim.x + threadIdx.x;
    if (e >= E) return;
    int r = rows[e];
    int c = nu + cols[e];
    int s1 = atomicAdd(&bcur[r >> BSHIFT], 1);
    recs[s1] = make_uint2((unsigned)r, (unsigned)c);
    int s2 = atomicAdd(&bcur[c >> BSHIFT], 1);
    recs[s2] = make_uint2((unsigned)c, (unsigned)r);
}

// ---------- pass B: per-bucket histogram + local exscan -> row_ptr + colidx ----------
__global__ void bucket_build(const uint2* __restrict__ recs, const int* __restrict__ bbase,
                             int* __restrict__ row_ptr, int* __restrict__ colidx,
                             int nn, int twoE) {
    __shared__ int pos[BWIDTH];       // histogram, then cursor
    __shared__ int scan_lds[BWIDTH];
    int b = blockIdx.x;
    int t = threadIdx.x;              // blockDim = BWIDTH = 256
    int start = bbase[b];
    int end   = bbase[b + 1];
    int node0 = b << BSHIFT;
    pos[t] = 0;
    __syncthreads();
    for (int i = start + t; i < end; i += BWIDTH)
        atomicAdd(&pos[recs[i].x - (unsigned)node0], 1);
    __syncthreads();
    int v = pos[t];
    scan_lds[t] = v; __syncthreads();
    for (int off = 1; off < BWIDTH; off <<= 1) {
        int add = (t >= off) ? scan_lds[t - off] : 0;
        __syncthreads();
        scan_lds[t] += add;
        __syncthreads();
    }
    int cur = start + scan_lds[t] - v;    // global exclusive offset for local node t
    pos[t] = cur;
    int node = node0 + t;
    if (node < nn) row_ptr[node] = cur;
    if (b == 0 && t == 0) row_ptr[nn] = twoE;
    __syncthreads();
    for (int i = start + t; i < end; i += BWIDTH) {
        uint2 rec = recs[i];
        int slot = atomicAdd(&pos[rec.x - (unsigned)node0], 1);
        colidx[slot] = (int)rec.y;
    }
}

// ---------- dinv from row_ptr ----------
__global__ void dinv_kernel(const int* __restrict__ row_ptr, float* __restrict__ dinv, int nn) {
    int i = blockIdx.x * blockDim.x + threadIdx.x;
    if (i < nn) dinv[i] = 1.0f / sqrtf(1e-7f + (float)(row_ptr[i + 1] - row_ptr[i]));
}

// ---------- pre-scale: x' = dinv ⊙ ego ----------
__global__ void prescale_kernel(const float* __restrict__ uemb, const float* __restrict__ iemb,
                                const float* __restrict__ dinv, float* __restrict__ xp,
                                int nu, int nn) {
    size_t i = (size_t)blockIdx.x * blockDim.x + threadIdx.x;
    if (i >= (size_t)nn * DIM) return;
    int node = (int)(i >> 6);
    float v = (node < nu) ? uemb[i] : iemb[i - (size_t)nu * DIM];
    xp[i] = v * dinv[node];
}

// ---------- fused gather-SpMM + cosine reweight + acc ----------
// one wave per destination node, lane = feature dim; xp is pre-scaled (dinv ⊙ x)
__global__ void spmm_fused(const int* __restrict__ row_ptr, const int* __restrict__ colidx,
                           const float* __restrict__ dinv,
                           const float* __restrict__ xp,
                           const float* __restrict__ eu, const float* __restrict__ ei,
                           float* __restrict__ ego_norm,
                           float* __restrict__ xn, float* __restrict__ acc,
                           int nu, int nn, int first, int last) {
    int node = (blockIdx.x * blockDim.x + threadIdx.x) >> 6;
    int lane = threadIdx.x & 63;
    if (node >= nn) return;
    int start = row_ptr[node];
    int end   = row_ptr[node + 1];
    float a = 0.0f;
    int j = start;
    for (; j + 8 <= end; j += 8) {
        int s[8];
#pragma unroll
        for (int k = 0; k < 8; ++k) s[k] = colidx[j + k];
        float v[8];
#pragma unroll
        for (int k = 0; k < 8; ++k) v[k] = xp[(size_t)s[k] * DIM + lane];
#pragma unroll
        for (int k = 0; k < 8; ++k) a += v[k];
    }
    if (j < end) {
        int s[8];
#pragma unroll
        for (int k = 0; k < 8; ++k) { int jj = j + k; s[k] = colidx[jj < end ? jj : end - 1]; }
        float v[8];
#pragma unroll
        for (int k = 0; k < 8; ++k) v[k] = (j + k < end) ? xp[(size_t)s[k] * DIM + lane] : 0.0f;
#pragma unroll
        for (int k = 0; k < 8; ++k) a += v[k];
    }
    float dn = dinv[node];
    a *= dn;
    size_t o = (size_t)node * DIM + lane;
    float ev = (node < nu) ? eu[o] : ei[o - (size_t)nu * DIM];
    float en;
    if (first) {
        en = fmaxf(sqrtf(wave_reduce_sum(ev * ev)), 1e-8f);
        if (lane == 0) ego_norm[node] = en;
    } else {
        en = ego_norm[node];
    }
    float dot = wave_reduce_sum(a * ev);
    float n2  = wave_reduce_sum(a * a);
    float w = dot / (fmaxf(sqrtf(n2), 1e-8f) * en);
    float y = w * a;
    if (!last)  xn[o] = y * dn;    // pre-scaled for next layer
    if (first)  acc[o] = y;
    else        acc[o] += y;
}

extern "C" void kernel_launch(void* const* d_in, const int* in_sizes, int n_in,
                              void* d_out, int out_size, void* d_ws, size_t ws_size,
                              hipStream_t stream) {
    const float* uemb = (const float*)d_in[0];
    const float* iemb = (const float*)d_in[1];
    const int*   rows = (const int*)d_in[2];
    const int*   cols = (const int*)d_in[3];
    // d_in[4] = n_layers; fixed at 3 (identical work per call required)

    const int nu = in_sizes[0] / DIM;
    const int ni = in_sizes[1] / DIM;
    const int E  = in_sizes[2];
    const int nn = nu + ni;
    const int nb = (nn + BWIDTH - 1) / BWIDTH;     // buckets (<= 4095 for exscan_small)

    // ---- workspace layout ----
    float* ws = (float*)d_ws;
    float* x1       = ws;                                  // nn*DIM f32
    float* x2       = x1 + (size_t)nn * DIM;               // nn*DIM f32
    int*   colidx   = (int*)(x2 + (size_t)nn * DIM);       // 2E int
    int*   row_ptr  = colidx + (size_t)2 * E;              // nn+1 int
    float* dinv     = (float*)(row_ptr + nn + 1);          // nn f32
    float* ego_norm = dinv + nn;                           // nn f32
    int*   bcnt     = (int*)(ego_norm + nn);               // nb int
    int*   bbase    = bcnt + nb;                           // nb+1 int
    int*   bcur     = bbase + nb + 1;                      // nb int
    uint2* recs     = (uint2*)x2;   // 2E * 8B records alias x2 (dead before x2 written)

    // ---- bucketed CSR build ----
    hipMemsetAsync(bcnt, 0, (size_t)nb * sizeof(int), stream);
    bucket_count<<<(E + 255) / 256, 256, 0, stream>>>(rows, cols, bcnt, nu, E);
    exscan_small<<<1, 1024, 0, stream>>>(bcnt, bbase, bcur, nb);
    scatter_recs<<<(E + 255) / 256, 256, 0, stream>>>(rows, cols, bcur, recs, nu, E);
    bucket_build<<<nb, BWIDTH, 0, stream>>>(recs, bbase, row_ptr, colidx, nn, 2 * E);
    dinv_kernel<<<(nn + 255) / 256, 256, 0, stream>>>(row_ptr, dinv, nn);

    // ---- prescale layer-0 input ----
    {
        size_t thr = (size_t)nn * DIM;
        prescale_kernel<<<(unsigned)((thr + 255) / 256), 256, 0, stream>>>(
            uemb, iemb, dinv, x1, nu, nn);
    }

    // ---- 3 fused SpMM+reweight layers ----
    unsigned gs = (unsigned)(((size_t)nn * 64 + 255) / 256);
    float* out = (float*)d_out;
    spmm_fused<<<gs, 256, 0, stream>>>(row_ptr, colidx, dinv, x1,
                                       uemb, iemb, ego_norm, x2, out, nu, nn, 1, 0);
    spmm_fused<<<gs, 256, 0, stream>>>(row_ptr, colidx, dinv, x2,
                                       uemb, iemb, ego_norm, x1, out, nu, nn, 0, 0);
    spmm_fused<<<gs, 256, 0, stream>>>(row_ptr, colidx, dinv, x1,
                                       uemb, iemb, ego_norm, x2, out, nu, nn, 0, 1);
}

// Round 5
// 1377.125 us; speedup vs baseline: 1.6643x; 1.6643x over previous
//
#include <hip/hip_runtime.h>

#define DIM 64
#define SBLK 1024  // elements per scan block (256 thr x 4)

// ---------- degree counting over combined node space ----------
__global__ void deg_kernel(const int* __restrict__ rows, const int* __restrict__ cols,
                           int* __restrict__ deg, int nu, int E) {
    int e = blockIdx.x * blockDim.x + threadIdx.x;
    if (e < E) {
        atomicAdd(&deg[rows[e]], 1);
        atomicAdd(&deg[nu + cols[e]], 1);
    }
}

__global__ void dinv_kernel(const int* __restrict__ deg, float* __restrict__ dinv, int nn) {
    int i = blockIdx.x * blockDim.x + threadIdx.x;
    if (i < nn) dinv[i] = 1.0f / sqrtf(1e-7f + (float)deg[i]);
}

// ---------- 3-kernel exclusive scan of deg -> row_ptr ----------
__global__ void scan_partial(const int* __restrict__ deg, int* __restrict__ bsum, int nn) {
    __shared__ int lds[256];
    int t = threadIdx.x;
    int base = blockIdx.x * SBLK + t * 4;
    int s = 0;
#pragma unroll
    for (int k = 0; k < 4; k++) { int i = base + k; if (i < nn) s += deg[i]; }
    lds[t] = s; __syncthreads();
    for (int off = 128; off >= 1; off >>= 1) {
        if (t < off) lds[t] += lds[t + off];
        __syncthreads();
    }
    if (t == 0) bsum[blockIdx.x] = lds[0];
}

__global__ void scan_sums(int* __restrict__ bsum, int nblocks, int* __restrict__ total) {
    __shared__ int lds[1024];
    int t = threadIdx.x;
    int v = (t < nblocks) ? bsum[t] : 0;
    lds[t] = v; __syncthreads();
    for (int off = 1; off < 1024; off <<= 1) {
        int add = (t >= off) ? lds[t - off] : 0;
        __syncthreads();
        lds[t] += add;
        __syncthreads();
    }
    if (t < nblocks) bsum[t] = lds[t] - v;
    if (t == nblocks - 1) *total = lds[t];
}

__global__ void scan_write(const int* __restrict__ deg, const int* __restrict__ bsum,
                           int* __restrict__ row_ptr, int nn) {
    __shared__ int lds[256];
    int t = threadIdx.x;
    int base = blockIdx.x * SBLK + t * 4;
    int d[4]; int s = 0;
#pragma unroll
    for (int k = 0; k < 4; k++) { int i = base + k; d[k] = (i < nn) ? deg[i] : 0; s += d[k]; }
    lds[t] = s; __syncthreads();
    for (int off = 1; off < 256; off <<= 1) {
        int add = (t >= off) ? lds[t - off] : 0;
        __syncthreads();
        lds[t] += add;
        __syncthreads();
    }
    int run = lds[t] - s + bsum[blockIdx.x];
#pragma unroll
    for (int k = 0; k < 4; k++) {
        int i = base + k;
        if (i < nn) row_ptr[i] = run;
        run += d[k];
    }
}

// ---------- CSR fill: both directions of each input edge ----------
__global__ void fill_kernel(const int* __restrict__ rows, const int* __restrict__ cols,
                            const int* __restrict__ row_ptr, int* __restrict__ cnt,
                            int* __restrict__ colidx, int nu, int E) {
    int e = blockIdx.x * blockDim.x + threadIdx.x;
    if (e >= E) return;
    int r = rows[e];
    int c = nu + cols[e];
    int p1 = atomicAdd(&cnt[r], 1);
    colidx[row_ptr[r] + p1] = c;
    int p2 = atomicAdd(&cnt[c], 1);
    colidx[row_ptr[c] + p2] = r;
}

// ---------- pre-scale: x' = dinv ⊙ ego (float4) ----------
__global__ void prescale_kernel(const float4* __restrict__ ue, const float4* __restrict__ ie,
                                const float* __restrict__ dinv, float4* __restrict__ xp,
                                int nu, int nn) {
    size_t i = (size_t)blockIdx.x * blockDim.x + threadIdx.x;
    if (i >= (size_t)nn * 16) return;
    int node = (int)(i >> 4);
    float4 v = (node < nu) ? ue[i] : ie[i - (size_t)nu * 16];
    float d = dinv[node];
    xp[i] = make_float4(v.x * d, v.y * d, v.z * d, v.w * d);
}

// ---------- fused gather-SpMM + cosine reweight + acc ----------
// wave = 4 nodes, 16 lanes per node, float4 per lane. xp pre-scaled (dinv ⊙ x).
__global__ void spmm_fused(const int* __restrict__ row_ptr, const int* __restrict__ colidx,
                           const float* __restrict__ dinv,
                           const float4* __restrict__ xp,
                           const float4* __restrict__ eu, const float4* __restrict__ ei,
                           float* __restrict__ ego_norm,
                           float4* __restrict__ xn, float4* __restrict__ acc,
                           int nu, int nn, int first, int last) {
    int wave = (blockIdx.x * blockDim.x + threadIdx.x) >> 6;
    int lane = threadIdx.x & 63;
    int sub  = lane >> 4;        // node within wave
    int li   = lane & 15;        // float4 index within row
    int node = wave * 4 + sub;
    bool valid = node < nn;
    int nclamp = valid ? node : nn - 1;
    int start = row_ptr[nclamp];
    int deg   = row_ptr[nclamp + 1] - start;
    if (!valid) deg = 0;
    int sbase = (deg > 0) ? start : 0;   // safe colidx index for padding lanes
    int md = deg;
#pragma unroll
    for (int m = 32; m >= 1; m >>= 1) md = max(md, __shfl_xor(md, m, 64));

    const float4 z = make_float4(0.f, 0.f, 0.f, 0.f);
    float4 a = z;
    int j = 0;
    for (; j + 8 <= md; j += 8) {
        int s[8];
#pragma unroll
        for (int k = 0; k < 8; ++k) { int jj = j + k; s[k] = colidx[jj < deg ? start + jj : sbase]; }
        float4 v[8];
#pragma unroll
        for (int k = 0; k < 8; ++k) v[k] = (j + k < deg) ? xp[(size_t)s[k] * 16 + li] : z;
#pragma unroll
        for (int k = 0; k < 8; ++k) { a.x += v[k].x; a.y += v[k].y; a.z += v[k].z; a.w += v[k].w; }
    }
    if (j < md) {
        int s[8];
#pragma unroll
        for (int k = 0; k < 8; ++k) { int jj = j + k; s[k] = colidx[jj < deg ? start + jj : sbase]; }
        float4 v[8];
#pragma unroll
        for (int k = 0; k < 8; ++k) v[k] = (j + k < deg) ? xp[(size_t)s[k] * 16 + li] : z;
#pragma unroll
        for (int k = 0; k < 8; ++k) { a.x += v[k].x; a.y += v[k].y; a.z += v[k].z; a.w += v[k].w; }
    }

    float dn = valid ? dinv[node] : 1.0f;
    a.x *= dn; a.y *= dn; a.z *= dn; a.w *= dn;

    size_t o = (size_t)nclamp * 16 + li;
    float4 ev = (nclamp < nu) ? eu[o] : ei[o - (size_t)nu * 16];
    float dp = a.x * ev.x + a.y * ev.y + a.z * ev.z + a.w * ev.w;
    float np = a.x * a.x + a.y * a.y + a.z * a.z + a.w * a.w;
    float ep = ev.x * ev.x + ev.y * ev.y + ev.z * ev.z + ev.w * ev.w;
#pragma unroll
    for (int m = 8; m >= 1; m >>= 1) {
        dp += __shfl_xor(dp, m, 64);
        np += __shfl_xor(np, m, 64);
        ep += __shfl_xor(ep, m, 64);
    }
    float en;
    if (first) {
        en = fmaxf(sqrtf(ep), 1e-8f);
        if (li == 0 && valid) ego_norm[node] = en;
    } else {
        en = valid ? ego_norm[node] : 1.0f;
    }
    float w = dp / (fmaxf(sqrtf(np), 1e-8f) * en);
    float4 y = make_float4(w * a.x, w * a.y, w * a.z, w * a.w);
    if (valid) {
        if (!last) xn[o] = make_float4(y.x * dn, y.y * dn, y.z * dn, y.w * dn);
        if (first) {
            acc[o] = y;
        } else {
            float4 t = acc[o];
            acc[o] = make_float4(t.x + y.x, t.y + y.y, t.z + y.z, t.w + y.w);
        }
    }
}

extern "C" void kernel_launch(void* const* d_in, const int* in_sizes, int n_in,
                              void* d_out, int out_size, void* d_ws, size_t ws_size,
                              hipStream_t stream) {
    const float* uemb = (const float*)d_in[0];
    const float* iemb = (const float*)d_in[1];
    const int*   rows = (const int*)d_in[2];
    const int*   cols = (const int*)d_in[3];
    // d_in[4] = n_layers; fixed at 3 (identical work per call required)

    const int nu = in_sizes[0] / DIM;
    const int ni = in_sizes[1] / DIM;
    const int E  = in_sizes[2];
    const int nn = nu + ni;

    // ---- workspace layout ----
    float* ws = (float*)d_ws;
    float* x1       = ws;                                  // nn*DIM f32
    float* x2       = x1 + (size_t)nn * DIM;               // nn*DIM f32
    int*   colidx   = (int*)(x2 + (size_t)nn * DIM);       // 2E int
    int*   row_ptr  = colidx + (size_t)2 * E;              // nn+1 int
    int*   deg      = row_ptr + (nn + 1);                  // nn int
    int*   cnt      = deg + nn;                            // nn int (adjacent to deg)
    float* dinv     = (float*)(cnt + nn);                  // nn f32
    float* ego_norm = dinv + nn;                           // nn f32
    int*   bsum     = (int*)(ego_norm + nn);               // <=1024 int

    // ---- build normalized CSR (R3 structure: 300K-way atomics, low contention) ----
    hipMemsetAsync(deg, 0, (size_t)2 * nn * sizeof(int), stream);   // deg + cnt
    deg_kernel<<<(E + 255) / 256, 256, 0, stream>>>(rows, cols, deg, nu, E);
    dinv_kernel<<<(nn + 255) / 256, 256, 0, stream>>>(deg, dinv, nn);

    int nb = (nn + SBLK - 1) / SBLK;
    scan_partial<<<nb, 256, 0, stream>>>(deg, bsum, nn);
    scan_sums<<<1, 1024, 0, stream>>>(bsum, nb, row_ptr + nn);
    scan_write<<<nb, 256, 0, stream>>>(deg, bsum, row_ptr, nn);
    fill_kernel<<<(E + 255) / 256, 256, 0, stream>>>(rows, cols, row_ptr, cnt, colidx, nu, E);

    // ---- prescale layer-0 input ----
    {
        size_t thr = (size_t)nn * 16;
        prescale_kernel<<<(unsigned)((thr + 255) / 256), 256, 0, stream>>>(
            (const float4*)uemb, (const float4*)iemb, dinv, (float4*)x1, nu, nn);
    }

    // ---- 3 fused SpMM+reweight layers (wave = 4 nodes) ----
    size_t waves = ((size_t)nn + 3) / 4;
    unsigned gs = (unsigned)((waves * 64 + 255) / 256);
    float* out = (float*)d_out;
    spmm_fused<<<gs, 256, 0, stream>>>(row_ptr, colidx, dinv, (const float4*)x1,
                                       (const float4*)uemb, (const float4*)iemb, ego_norm,
                                       (float4*)x2, (float4*)out, nu, nn, 1, 0);
    spmm_fused<<<gs, 256, 0, stream>>>(row_ptr, colidx, dinv, (const float4*)x2,
                                       (const float4*)uemb, (const float4*)iemb, ego_norm,
                                       (float4*)x1, (float4*)out, nu, nn, 0, 0);
    spmm_fused<<<gs, 256, 0, stream>>>(row_ptr, colidx, dinv, (const float4*)x1,
                                       (const float4*)uemb, (const float4*)iemb, ego_norm,
                                       (float4*)x2, (float4*)out, nu, nn, 0, 1);
}

// Round 6
// 1021.133 us; speedup vs baseline: 2.2446x; 1.3486x over previous
//
#include <hip/hip_runtime.h>

#define DIM 64
#define SBLK 1024  // elements per scan block (256 thr x 4)

typedef __attribute__((ext_vector_type(4))) _Float16 half4;

// ---------- degree counting over combined node space ----------
__global__ void deg_kernel(const int* __restrict__ rows, const int* __restrict__ cols,
                           int* __restrict__ deg, int nu, int E) {
    int e = blockIdx.x * blockDim.x + threadIdx.x;
    if (e < E) {
        atomicAdd(&deg[rows[e]], 1);
        atomicAdd(&deg[nu + cols[e]], 1);
    }
}

__global__ void dinv_kernel(const int* __restrict__ deg, float* __restrict__ dinv, int nn) {
    int i = blockIdx.x * blockDim.x + threadIdx.x;
    if (i < nn) dinv[i] = 1.0f / sqrtf(1e-7f + (float)deg[i]);
}

// ---------- 3-kernel exclusive scan of deg -> row_ptr ----------
__global__ void scan_partial(const int* __restrict__ deg, int* __restrict__ bsum, int nn) {
    __shared__ int lds[256];
    int t = threadIdx.x;
    int base = blockIdx.x * SBLK + t * 4;
    int s = 0;
#pragma unroll
    for (int k = 0; k < 4; k++) { int i = base + k; if (i < nn) s += deg[i]; }
    lds[t] = s; __syncthreads();
    for (int off = 128; off >= 1; off >>= 1) {
        if (t < off) lds[t] += lds[t + off];
        __syncthreads();
    }
    if (t == 0) bsum[blockIdx.x] = lds[0];
}

__global__ void scan_sums(int* __restrict__ bsum, int nblocks, int* __restrict__ total) {
    __shared__ int lds[1024];
    int t = threadIdx.x;
    int v = (t < nblocks) ? bsum[t] : 0;
    lds[t] = v; __syncthreads();
    for (int off = 1; off < 1024; off <<= 1) {
        int add = (t >= off) ? lds[t - off] : 0;
        __syncthreads();
        lds[t] += add;
        __syncthreads();
    }
    if (t < nblocks) bsum[t] = lds[t] - v;
    if (t == nblocks - 1) *total = lds[t];
}

__global__ void scan_write(const int* __restrict__ deg, const int* __restrict__ bsum,
                           int* __restrict__ row_ptr, int nn) {
    __shared__ int lds[256];
    int t = threadIdx.x;
    int base = blockIdx.x * SBLK + t * 4;
    int d[4]; int s = 0;
#pragma unroll
    for (int k = 0; k < 4; k++) { int i = base + k; d[k] = (i < nn) ? deg[i] : 0; s += d[k]; }
    lds[t] = s; __syncthreads();
    for (int off = 1; off < 256; off <<= 1) {
        int add = (t >= off) ? lds[t - off] : 0;
        __syncthreads();
        lds[t] += add;
        __syncthreads();
    }
    int run = lds[t] - s + bsum[blockIdx.x];
#pragma unroll
    for (int k = 0; k < 4; k++) {
        int i = base + k;
        if (i < nn) row_ptr[i] = run;
        run += d[k];
    }
}

// ---------- CSR fill: both directions of each input edge ----------
__global__ void fill_kernel(const int* __restrict__ rows, const int* __restrict__ cols,
                            const int* __restrict__ row_ptr, int* __restrict__ cnt,
                            int* __restrict__ colidx, int nu, int E) {
    int e = blockIdx.x * blockDim.x + threadIdx.x;
    if (e >= E) return;
    int r = rows[e];
    int c = nu + cols[e];
    int p1 = atomicAdd(&cnt[r], 1);
    colidx[row_ptr[r] + p1] = c;
    int p2 = atomicAdd(&cnt[c], 1);
    colidx[row_ptr[c] + p2] = r;
}

// ---------- pre-scale: x' = dinv ⊙ ego, stored fp16 ----------
__global__ void prescale_kernel(const float4* __restrict__ ue, const float4* __restrict__ ie,
                                const float* __restrict__ dinv, half4* __restrict__ xp,
                                int nu, int nn) {
    size_t i = (size_t)blockIdx.x * blockDim.x + threadIdx.x;
    if (i >= (size_t)nn * 16) return;
    int node = (int)(i >> 4);
    float4 v = (node < nu) ? ue[i] : ie[i - (size_t)nu * 16];
    float d = dinv[node];
    half4 h;
    h.x = (_Float16)(v.x * d); h.y = (_Float16)(v.y * d);
    h.z = (_Float16)(v.z * d); h.w = (_Float16)(v.w * d);
    xp[i] = h;
}

// ---------- fused gather-SpMM + cosine reweight + acc ----------
// one wave per node; 4 sub-groups of 16 lanes handle 4 consecutive edges;
// each lane loads half4 (8 B). xp is pre-scaled fp16 (dinv ⊙ x).
__global__ void spmm_fused(const int* __restrict__ row_ptr, const int* __restrict__ colidx,
                           const float* __restrict__ dinv,
                           const half4* __restrict__ xp,
                           const float4* __restrict__ eu, const float4* __restrict__ ei,
                           float* __restrict__ ego_norm,
                           half4* __restrict__ xn, float4* __restrict__ acc,
                           int nu, int nn, int first, int last) {
    int node = (blockIdx.x * blockDim.x + threadIdx.x) >> 6;
    int lane = threadIdx.x & 63;
    int sub  = lane >> 4;        // edge slot within step
    int li   = lane & 15;        // half4 index within row
    if (node >= nn) return;
    int start = row_ptr[node];
    int deg   = row_ptr[node + 1] - start;

    float ax = 0.f, ay = 0.f, az = 0.f, aw = 0.f;
    int j = 0;
    // full 8-edge steps: no predication, 2 gathers per lane in flight
    for (; j + 8 <= deg; j += 8) {
        int s0 = colidx[start + j + sub];
        int s1 = colidx[start + j + 4 + sub];
        half4 h0 = xp[(size_t)s0 * 16 + li];
        half4 h1 = xp[(size_t)s1 * 16 + li];
        ax += (float)h0.x + (float)h1.x;
        ay += (float)h0.y + (float)h1.y;
        az += (float)h0.z + (float)h1.z;
        aw += (float)h0.w + (float)h1.w;
    }
    // single predicated 8-wide tail
    if (j < deg) {
        int j0 = j + sub, j1 = j + 4 + sub;
        int s0 = colidx[j0 < deg ? start + j0 : start];
        int s1 = colidx[j1 < deg ? start + j1 : start];
        if (j0 < deg) {
            half4 h = xp[(size_t)s0 * 16 + li];
            ax += (float)h.x; ay += (float)h.y; az += (float)h.z; aw += (float)h.w;
        }
        if (j1 < deg) {
            half4 h = xp[(size_t)s1 * 16 + li];
            ax += (float)h.x; ay += (float)h.y; az += (float)h.z; aw += (float)h.w;
        }
    }
    // merge partial sums across the 4 sub-groups
#pragma unroll
    for (int m = 32; m >= 16; m >>= 1) {
        ax += __shfl_xor(ax, m, 64);
        ay += __shfl_xor(ay, m, 64);
        az += __shfl_xor(az, m, 64);
        aw += __shfl_xor(aw, m, 64);
    }
    float dn = dinv[node];
    ax *= dn; ay *= dn; az *= dn; aw *= dn;

    size_t o = (size_t)node * 16 + li;
    float4 ev = (node < nu) ? eu[o] : ei[o - (size_t)nu * 16];
    float dp = ax * ev.x + ay * ev.y + az * ev.z + aw * ev.w;
    float np = ax * ax + ay * ay + az * az + aw * aw;
    float ep = ev.x * ev.x + ev.y * ev.y + ev.z * ev.z + ev.w * ev.w;
#pragma unroll
    for (int m = 8; m >= 1; m >>= 1) {
        dp += __shfl_xor(dp, m, 64);
        np += __shfl_xor(np, m, 64);
        ep += __shfl_xor(ep, m, 64);
    }
    float en;
    if (first) {
        en = fmaxf(sqrtf(ep), 1e-8f);
        if (lane == 0) ego_norm[node] = en;
    } else {
        en = ego_norm[node];
    }
    float w = dp / (fmaxf(sqrtf(np), 1e-8f) * en);
    float yx = w * ax, yy = w * ay, yz = w * az, yw = w * aw;
    if (sub == 0) {
        if (!last) {
            half4 h;
            h.x = (_Float16)(yx * dn); h.y = (_Float16)(yy * dn);
            h.z = (_Float16)(yz * dn); h.w = (_Float16)(yw * dn);
            xn[o] = h;
        }
        if (first) {
            acc[o] = make_float4(yx, yy, yz, yw);
        } else {
            float4 t = acc[o];
            acc[o] = make_float4(t.x + yx, t.y + yy, t.z + yz, t.w + yw);
        }
    }
}

extern "C" void kernel_launch(void* const* d_in, const int* in_sizes, int n_in,
                              void* d_out, int out_size, void* d_ws, size_t ws_size,
                              hipStream_t stream) {
    const float* uemb = (const float*)d_in[0];
    const float* iemb = (const float*)d_in[1];
    const int*   rows = (const int*)d_in[2];
    const int*   cols = (const int*)d_in[3];
    // d_in[4] = n_layers; fixed at 3 (identical work per call required)

    const int nu = in_sizes[0] / DIM;
    const int ni = in_sizes[1] / DIM;
    const int E  = in_sizes[2];
    const int nn = nu + ni;

    // ---- workspace layout ----
    char* ws = (char*)d_ws;
    half4* x1      = (half4*)ws;                            // nn*16 half4 (128 B/node)
    half4* x2      = x1 + (size_t)nn * 16;                  // nn*16 half4
    int*   colidx  = (int*)(x2 + (size_t)nn * 16);          // 2E int
    int*   row_ptr = colidx + (size_t)2 * E;                // nn+1 int
    int*   deg     = row_ptr + (nn + 1);                    // nn int
    int*   cnt     = deg + nn;                              // nn int (adjacent to deg)
    float* dinv    = (float*)(cnt + nn);                    // nn f32
    float* ego_norm= dinv + nn;                             // nn f32
    int*   bsum    = (int*)(ego_norm + nn);                 // <=1024 int

    // ---- build normalized CSR (R3 structure: 300K-way atomics, low contention) ----
    hipMemsetAsync(deg, 0, (size_t)2 * nn * sizeof(int), stream);   // deg + cnt
    deg_kernel<<<(E + 255) / 256, 256, 0, stream>>>(rows, cols, deg, nu, E);
    dinv_kernel<<<(nn + 255) / 256, 256, 0, stream>>>(deg, dinv, nn);

    int nb = (nn + SBLK - 1) / SBLK;
    scan_partial<<<nb, 256, 0, stream>>>(deg, bsum, nn);
    scan_sums<<<1, 1024, 0, stream>>>(bsum, nb, row_ptr + nn);
    scan_write<<<nb, 256, 0, stream>>>(deg, bsum, row_ptr, nn);
    fill_kernel<<<(E + 255) / 256, 256, 0, stream>>>(rows, cols, row_ptr, cnt, colidx, nu, E);

    // ---- prescale layer-0 input (fp32 ego -> fp16 x') ----
    {
        size_t thr = (size_t)nn * 16;
        prescale_kernel<<<(unsigned)((thr + 255) / 256), 256, 0, stream>>>(
            (const float4*)uemb, (const float4*)iemb, dinv, x1, nu, nn);
    }

    // ---- 3 fused SpMM+reweight layers (one node per wave) ----
    unsigned gs = (unsigned)(((size_t)nn * 64 + 255) / 256);
    float4* out = (float4*)d_out;
    spmm_fused<<<gs, 256, 0, stream>>>(row_ptr, colidx, dinv, x1,
                                       (const float4*)uemb, (const float4*)iemb, ego_norm,
                                       x2, out, nu, nn, 1, 0);
    spmm_fused<<<gs, 256, 0, stream>>>(row_ptr, colidx, dinv, x2,
                                       (const float4*)uemb, (const float4*)iemb, ego_norm,
                                       x1, out, nu, nn, 0, 0);
    spmm_fused<<<gs, 256, 0, stream>>>(row_ptr, colidx, dinv, x1,
                                       (const float4*)uemb, (const float4*)iemb, ego_norm,
                                       x2, out, nu, nn, 0, 1);
}